// Round 1
// baseline (571.926 us; speedup 1.0000x reference)
//
#include <hip/hip_runtime.h>
#include <math.h>

// Problem constants (match reference)
constexpr int Bn = 4, Rn = 16384, Sn = 48, Cn = 32;
constexpr int NRAY = Bn * Rn;                 // 65536 rays
constexpr int SM1  = Sn - 1;                  // 47 segments
constexpr int OUT_DEPTH_OFF = NRAY * Cn;      // rgb block size
constexpr int OUT_W_OFF     = OUT_DEPTH_OFF + NRAY;

// ---- pass 0: init global min/max cells in workspace --------------------
__global__ void k_init(unsigned int* ws) {
  ws[0] = 0xFFFFFFFFu;  // running min (uint order == float order for positives)
  ws[1] = 0u;           // running max
}

// ---- pass 1: global min/max of depths (sorted per ray -> first/last) ---
__global__ void k_minmax(const float* __restrict__ depths, unsigned int* ws) {
  int ray = blockIdx.x * blockDim.x + threadIdx.x;
  float lo = depths[(size_t)ray * Sn];
  float hi = depths[(size_t)ray * Sn + (Sn - 1)];
#pragma unroll
  for (int off = 32; off > 0; off >>= 1) {
    lo = fminf(lo, __shfl_down(lo, off, 64));
    hi = fmaxf(hi, __shfl_down(hi, off, 64));
  }
  __shared__ float slo[4], shi[4];
  int wv = threadIdx.x >> 6;
  if ((threadIdx.x & 63) == 0) { slo[wv] = lo; shi[wv] = hi; }
  __syncthreads();
  if (threadIdx.x == 0) {
    for (int i = 1; i < 4; ++i) { lo = fminf(lo, slo[i]); hi = fmaxf(hi, shi[i]); }
    atomicMin(ws + 0, __float_as_uint(lo));
    atomicMax(ws + 1, __float_as_uint(hi));
  }
}

// ---- pass 2: ray march. 8 lanes per ray (float4 over C), wave = 8 rays -
__global__ __launch_bounds__(256) void k_march(
    const float* __restrict__ colors,
    const float* __restrict__ dens,
    const float* __restrict__ deps,
    const unsigned int* __restrict__ ws,
    float* __restrict__ out) {
  const int tid      = threadIdx.x;
  const int lane     = tid & 7;        // float4 chunk within ray (C/4 = 8)
  const int rayInBlk = tid >> 3;       // 0..31
  const int ray      = blockIdx.x * 32 + rayInBlk;

  const float4* __restrict__ cp =
      (const float4*)(colors + (size_t)ray * (Sn * Cn)) + lane;  // stride 8 float4 per step
  const float* __restrict__ dp = dens + (size_t)ray * Sn;
  const float* __restrict__ zp = deps + (size_t)ray * Sn;

  // weights staging: stride 49 floats -> active lanes hit distinct banks
  __shared__ float wlds[32 * 49];

  float4 ca = cp[0];
  float  da = dp[0], za = zp[0];
  float4 cb = cp[8];
  float  db = dp[1], zb = zp[1];

  float T = 1.0f;
  float rx = 0.f, ry = 0.f, rz = 0.f, rw = 0.f;
  float wsum = 0.f, dsum = 0.f;

  for (int s = 0; s < SM1; ++s) {
    // prefetch step s+2 (clamped; last-ray safe)
    int sp2 = (s + 2 < Sn) ? (s + 2) : (Sn - 1);
    float4 cc = cp[sp2 * 8];
    float  dc = dp[sp2];
    float  zc = zp[sp2];

    float delta = zb - za;
    float x     = 0.5f * (da + db) - 1.0f;
    float sp    = fmaxf(x, 0.0f) + log1pf(expf(-fabsf(x)));  // jax softplus
    float alpha = 1.0f - expf(-sp * delta);
    float w     = alpha * T;
    T           = T * (1.0f - alpha + 1e-10f);

    rx += w * (0.5f * (ca.x + cb.x));
    ry += w * (0.5f * (ca.y + cb.y));
    rz += w * (0.5f * (ca.z + cb.z));
    rw += w * (0.5f * (ca.w + cb.w));
    wsum += w;
    dsum += w * (0.5f * (za + zb));

    if (lane == (s & 7)) wlds[rayInBlk * 49 + s] = w;  // one lane per ray

    ca = cb; da = db; za = zb;
    cb = cc; db = dc; zb = zc;
  }

  // composite_rgb = rgb*2-1, coalesced float4 store
  float4 o;
  o.x = rx * 2.f - 1.f; o.y = ry * 2.f - 1.f;
  o.z = rz * 2.f - 1.f; o.w = rw * 2.f - 1.f;
  ((float4*)(out + (size_t)ray * Cn))[lane] = o;

  if (lane == 0) {
    float cd = dsum / wsum;
    if (cd != cd) cd = INFINITY;  // nan_to_num(nan=inf)
    float dmin = __uint_as_float(ws[0]);
    float dmax = __uint_as_float(ws[1]);
    cd = fminf(fmaxf(cd, dmin), dmax);
    out[OUT_DEPTH_OFF + ray] = cd;
  }

  // coalesced weights writeback
  __syncthreads();
  float* wout = out + OUT_W_OFF + (size_t)blockIdx.x * (32 * SM1);
  for (int i = tid; i < 32 * SM1; i += 256) {
    int r = i / SM1;
    int s = i - r * SM1;
    wout[i] = wlds[r * 49 + s];
  }
}

extern "C" void kernel_launch(void* const* d_in, const int* in_sizes, int n_in,
                              void* d_out, int out_size, void* d_ws, size_t ws_size,
                              hipStream_t stream) {
  const float* colors = (const float*)d_in[0];
  const float* dens   = (const float*)d_in[1];
  const float* deps   = (const float*)d_in[2];
  float* out          = (float*)d_out;
  unsigned int* ws    = (unsigned int*)d_ws;

  k_init<<<1, 1, 0, stream>>>(ws);
  k_minmax<<<NRAY / 256, 256, 0, stream>>>(deps, ws);
  k_march<<<NRAY / 32, 256, 0, stream>>>(colors, dens, deps, ws, out);
}